// Round 1
// baseline (824.825 us; speedup 1.0000x reference)
//
#include <hip/hip_runtime.h>
#include <hip/hip_bf16.h>
#include <math.h>

#define MM 4096
#define KK 768
#define PADI(m) ((m) + ((m) >> 4))

// ---------------- normalize rows ----------------
__global__ __launch_bounds__(256) void knorm(const float* __restrict__ emb,
                                             float* __restrict__ normed) {
  int row = blockIdx.x;
  int tid = threadIdx.x;
  const float* e = emb + (size_t)row * KK;
  float v0 = e[tid], v1 = e[tid + 256], v2 = e[tid + 512];
  float ss = v0 * v0 + v1 * v1 + v2 * v2;
  for (int s = 32; s; s >>= 1) ss += __shfl_down(ss, s, 64);
  __shared__ float red[4];
  if ((tid & 63) == 0) red[tid >> 6] = ss;
  __syncthreads();
  float tot = red[0] + red[1] + red[2] + red[3];
  float inv = 1.f / fmaxf(sqrtf(tot), 1e-12f);
  float* o = normed + (size_t)row * KK;
  o[tid] = v0 * inv;
  o[tid + 256] = v1 * inv;
  o[tid + 512] = v2 * inv;
}

// ---------------- rank-sort labels per dim ----------------
// grid = 32 blocks: d = b>>4, slice = b&15. Each thread ranks one element.
__global__ __launch_bounds__(256) void ksort(const float* __restrict__ labels,
                                             float* __restrict__ slab,
                                             int* __restrict__ perm,
                                             int* __restrict__ pos) {
  __shared__ float lab[MM];
  int d = blockIdx.x >> 4;
  int slice = blockIdx.x & 15;
  for (int i = threadIdx.x; i < MM; i += 256) lab[i] = labels[(size_t)i * 2 + d];
  __syncthreads();
  int i = slice * 256 + threadIdx.x;
  float v = lab[i];
  int r = 0;
  for (int k = 0; k < MM; ++k) {
    float w = lab[k];
    r += (w < v) || (w == v && k < i);
  }
  slab[d * MM + r] = v;
  perm[d * MM + r] = i;
  pos[d * MM + i] = r;
}

// ---------------- fp32 GEMM: exp_sims chunk = exp(10 * A·A^T) ----------------
// 128x128 tile, BK=16, 256 threads, 8x8 micro-tile.
__global__ __launch_bounds__(256) void kgemm(const float* __restrict__ A,
                                             int rowBase,
                                             float* __restrict__ out) {
  __shared__ __align__(16) float As[16 * 128];
  __shared__ __align__(16) float Bs[16 * 128];
  int tid = threadIdx.x;
  int col0 = blockIdx.x * 128;
  int row0 = rowBase + blockIdx.y * 128;
  int tr = tid >> 4, tc = tid & 15;

  float acc[8][8];
#pragma unroll
  for (int u = 0; u < 8; ++u)
#pragma unroll
    for (int v = 0; v < 8; ++v) acc[u][v] = 0.f;

  for (int k0 = 0; k0 < KK; k0 += 16) {
    __syncthreads();
#pragma unroll
    for (int q = 0; q < 2; ++q) {
      int l = tid + 256 * q;
      int r = l >> 2, seg = l & 3;
      float4 va = *(const float4*)(A + (size_t)(row0 + r) * KK + k0 + seg * 4);
      As[(seg * 4 + 0) * 128 + r] = va.x;
      As[(seg * 4 + 1) * 128 + r] = va.y;
      As[(seg * 4 + 2) * 128 + r] = va.z;
      As[(seg * 4 + 3) * 128 + r] = va.w;
      float4 vb = *(const float4*)(A + (size_t)(col0 + r) * KK + k0 + seg * 4);
      Bs[(seg * 4 + 0) * 128 + r] = vb.x;
      Bs[(seg * 4 + 1) * 128 + r] = vb.y;
      Bs[(seg * 4 + 2) * 128 + r] = vb.z;
      Bs[(seg * 4 + 3) * 128 + r] = vb.w;
    }
    __syncthreads();
#pragma unroll
    for (int kk = 0; kk < 16; ++kk) {
      float a[8], b[8];
      *(float4*)(a) = *(float4*)&As[kk * 128 + tr * 8];
      *(float4*)(a + 4) = *(float4*)&As[kk * 128 + tr * 8 + 4];
      *(float4*)(b) = *(float4*)&Bs[kk * 128 + tc * 8];
      *(float4*)(b + 4) = *(float4*)&Bs[kk * 128 + tc * 8 + 4];
#pragma unroll
      for (int u = 0; u < 8; ++u)
#pragma unroll
        for (int v = 0; v < 8; ++v) acc[u][v] = fmaf(a[u], b[v], acc[u][v]);
    }
  }

  int rloc0 = (row0 - rowBase) + tr * 8;
#pragma unroll
  for (int u = 0; u < 8; ++u) {
    float4 o1, o2;
    o1.x = expf(acc[u][0] * 10.f);
    o1.y = expf(acc[u][1] * 10.f);
    o1.z = expf(acc[u][2] * 10.f);
    o1.w = expf(acc[u][3] * 10.f);
    o2.x = expf(acc[u][4] * 10.f);
    o2.y = expf(acc[u][5] * 10.f);
    o2.z = expf(acc[u][6] * 10.f);
    o2.w = expf(acc[u][7] * 10.f);
    float* p = out + (size_t)(rloc0 + u) * MM + col0 + tc * 8;
    *(float4*)(p) = o1;
    *(float4*)(p + 4) = o2;
  }
}

// ---------------- per-row loss ----------------
__global__ __launch_bounds__(256) void kloss(const float* __restrict__ expchunk,
                                             int rowBase,
                                             const float* __restrict__ labels,
                                             const float* __restrict__ slab_g,
                                             const int* __restrict__ perm_g,
                                             const int* __restrict__ pos_g,
                                             float* __restrict__ part_logd,
                                             float* __restrict__ part_sims) {
  const int i = rowBase + blockIdx.x;
  const float* row = expchunk + (size_t)blockIdx.x * MM;
  __shared__ float E_[PADI(MM) + 1];
  __shared__ float S_[PADI(MM) + 1];
  __shared__ float slab[MM];
  __shared__ float sc[256];
  __shared__ float rs[256];
  __shared__ float red[4];
  int tid = threadIdx.x;

  // pass 0: sum_{j != i} sims[i][j] == sum log(exp_sims)
  float ssum = 0.f;
  for (int j = tid; j < MM; j += 256)
    if (j != i) ssum += logf(row[j]);
  for (int s = 32; s; s >>= 1) ssum += __shfl_down(ssum, s, 64);
  if ((tid & 63) == 0) red[tid >> 6] = ssum;
  __syncthreads();
  if (tid == 0) part_sims[i] = red[0] + red[1] + red[2] + red[3];

  for (int d = 0; d < 2; ++d) {
    __syncthreads();  // protect slab/E_/S_/red from previous phase readers
    for (int m = tid; m < MM; m += 256) slab[m] = slab_g[d * MM + m];

    // gather into sorted order; per-thread contiguous chunk of 16
    float g[16];
    int m0 = tid * 16;
    const int* pm = perm_g + d * MM + m0;
    float ls = 0.f;
#pragma unroll
    for (int u = 0; u < 16; ++u) {
      g[u] = row[pm[u]];
      ls += g[u];
    }
    sc[tid] = ls;
    rs[tid] = ls;
    __syncthreads();
    // forward + reverse inclusive Hillis-Steele scans
    for (int s = 1; s < 256; s <<= 1) {
      float va = (tid >= s) ? sc[tid - s] : 0.f;
      float vb = (tid + s < 256) ? rs[tid + s] : 0.f;
      __syncthreads();
      sc[tid] += va;
      rs[tid] += vb;
      __syncthreads();
    }
    float total = sc[255];
    float eoff = (tid > 0) ? sc[tid - 1] : 0.f;
    float soff = (tid < 255) ? rs[tid + 1] : 0.f;
    float run = eoff;
#pragma unroll
    for (int u = 0; u < 16; ++u) {
      E_[PADI(m0 + u)] = run;
      run += g[u];
    }
    float run2 = soff;
#pragma unroll
    for (int u = 15; u >= 0; --u) {
      run2 += g[u];
      S_[PADI(m0 + u)] = run2;
    }
    if (tid == 0) {
      E_[PADI(MM)] = total;
      S_[PADI(MM)] = 0.f;
    }
    __syncthreads();

    const int pi = pos_g[d * MM + i];
    const float c = slab[pi];
    float acc = 0.f;
    for (int j = tid; j < MM; j += 256) {
      if (j == i) continue;
      float lj = labels[(size_t)j * 2 + d];
      float t = fabsf(lj - c);
      float denom;
      if (t == 0.f) {
        denom = total;  // all dists >= 0
      } else {
        // lo = first m in [0, pi] with |slab[m]-c| < t   (dist decreasing there)
        int a = 0, b = pi;
        while (a < b) {
          int mid = (a + b) >> 1;
          if (fabsf(slab[mid] - c) < t) b = mid; else a = mid + 1;
        }
        int lo = a;
        // hi = first m in [pi, M] with |slab[m]-c| >= t  (dist increasing there)
        a = pi; b = MM;
        while (a < b) {
          int mid = (a + b) >> 1;
          if (fabsf(slab[mid] - c) >= t) b = mid; else a = mid + 1;
        }
        int hi = a;
        denom = E_[PADI(lo)] + S_[PADI(hi)];
      }
      denom = fmaxf(denom, 1e-7f);
      acc += logf(denom);
    }
    for (int s = 32; s; s >>= 1) acc += __shfl_down(acc, s, 64);
    __syncthreads();
    if ((tid & 63) == 0) red[tid >> 6] = acc;
    __syncthreads();
    if (tid == 0) part_logd[d * MM + i] = red[0] + red[1] + red[2] + red[3];
  }
}

// ---------------- final reduce (double) ----------------
__global__ __launch_bounds__(256) void kreduce(const float* __restrict__ part_logd,
                                               const float* __restrict__ part_sims,
                                               float* __restrict__ out) {
  int tid = threadIdx.x;
  double s0 = 0.0, s1 = 0.0, ss = 0.0;
  for (int i = tid; i < MM; i += 256) {
    s0 += (double)part_logd[i];
    s1 += (double)part_logd[MM + i];
    ss += (double)part_sims[i];
  }
  for (int s = 32; s; s >>= 1) {
    s0 += __shfl_down(s0, s, 64);
    s1 += __shfl_down(s1, s, 64);
    ss += __shfl_down(ss, s, 64);
  }
  __shared__ double red[3][4];
  if ((tid & 63) == 0) {
    red[0][tid >> 6] = s0;
    red[1][tid >> 6] = s1;
    red[2][tid >> 6] = ss;
  }
  __syncthreads();
  if (tid == 0) {
    double t0 = red[0][0] + red[0][1] + red[0][2] + red[0][3];
    double t1 = red[1][0] + red[1][1] + red[1][2] + red[1][3];
    double ts = red[2][0] + red[2][1] + red[2][2] + red[2][3];
    double n = (double)MM * (double)(MM - 1);
    out[0] = (float)((t0 - ts) / n);
    out[1] = (float)((t1 - ts) / n);
  }
}

extern "C" void kernel_launch(void* const* d_in, const int* in_sizes, int n_in,
                              void* d_out, int out_size, void* d_ws, size_t ws_size,
                              hipStream_t stream) {
  const float* emb = (const float*)d_in[0];
  const float* labels = (const float*)d_in[1];
  float* out = (float*)d_out;
  char* ws = (char*)d_ws;

  size_t off = 0;
  auto alloc = [&](size_t bytes) {
    void* p = ws + off;
    off = (off + bytes + 255) & ~(size_t)255;
    return p;
  };
  float* normed = (float*)alloc((size_t)MM * KK * 4);
  float* slab = (float*)alloc((size_t)2 * MM * 4);
  int* perm = (int*)alloc((size_t)2 * MM * 4);
  int* pos = (int*)alloc((size_t)2 * MM * 4);
  float* part_logd = (float*)alloc((size_t)2 * MM * 4);
  float* part_sims = (float*)alloc((size_t)MM * 4);
  size_t fixed = off;

  size_t avail = (ws_size > fixed) ? (ws_size - fixed) : 0;
  long long cr = (long long)(avail / ((size_t)MM * 4));
  cr = (cr / 128) * 128;
  if (cr > MM) cr = MM;
  if (cr < 128) cr = 128;  // minimum viable; assumes ws_size >= ~15 MB
  int chunk_rows = (int)cr;
  float* expchunk = (float*)(ws + fixed);

  knorm<<<MM, 256, 0, stream>>>(emb, normed);
  ksort<<<32, 256, 0, stream>>>(labels, slab, perm, pos);

  for (int base = 0; base < MM; base += chunk_rows) {
    int rows = MM - base < chunk_rows ? MM - base : chunk_rows;
    kgemm<<<dim3(MM / 128, rows / 128), 256, 0, stream>>>(normed, base, expchunk);
    kloss<<<rows, 256, 0, stream>>>(expchunk, base, labels, slab, perm, pos,
                                    part_logd, part_sims);
  }
  kreduce<<<1, 256, 0, stream>>>(part_logd, part_sims, out);
}